// Round 18
// baseline (1386.916 us; speedup 1.0000x reference)
//
#include <hip/hip_runtime.h>
#include <cfloat>
#include <cstdint>

// Problem constants
constexpr int Bn   = 16;
constexpr int Nn   = 2048;
constexpr int Fin  = 8;
constexpr int Kn   = 35;
constexpr int NODES = Bn * Nn;          // 32768
constexpr int EDG   = NODES * Kn;       // 1146880
constexpr int NSTATB = 1024;            // stats grid blocks
constexpr float EPSV = 1e-5f;

typedef _Float16 f16;
typedef _Float16 f16x2 __attribute__((ext_vector_type(2)));

// ---- monotone float<->u32 encoding for ordered compare / atomic max ----
__device__ __forceinline__ unsigned enc_f(float f){
    unsigned u = __float_as_uint(f);
    return (u & 0x80000000u) ? ~u : (u | 0x80000000u);
}
__device__ __forceinline__ float dec_f(unsigned e){
    unsigned u = (e & 0x80000000u) ? (e ^ 0x80000000u) : ~e;
    return __uint_as_float(u);
}

// ---- squared norms per node ----
template<int C>
__global__ __launch_bounds__(256) void sq_kernel(const float* __restrict__ h, float* __restrict__ sq){
    int i = blockIdx.x * 256 + threadIdx.x;
    if (i >= NODES) return;
    const float* p = h + (size_t)i * C;
    float s = 0.f;
#pragma unroll
    for (int c = 0; c < C; c++) s += p[c] * p[c];
    sq[i] = s;
}

// ---- kNN: 4 queries per block, 512 threads (8 waves) — occupancy was THE only
// lever that ever moved this kernel (11%->44% gave 960->529; sweep micro-opts x4
// all neutral). Same 38.5KB LDS with 8 waves -> 32 waves/CU (100%).
// Select: 2 waves per query (each owns 16 of 32 slot-rows), counts combined via
// LDS + block barriers; refine = fixed 4 barrier-synced iterations (flags gate
// math, every wave executes every barrier). Compaction order identical to the
// 1-wave version -> identical selected sets (exact counts + exact rank).
template<int C>
__global__ __launch_bounds__(512) void knn_kernel(const float* __restrict__ h, const float* __restrict__ sq,
                                                  int* __restrict__ idxout){
    __shared__ float dist[4][Nn];                  // 32 KB
    __shared__ float hi4[4][C];
    __shared__ float sqi[4];
    __shared__ float statred[4][3][8];             // [query][sum|ssq|min][wave]
    __shared__ int   cntred[4][6][2];              // [query][pivot/slot][half]
    __shared__ unsigned long long keybuf[4][128];  // 4 KB candidate keys
    int t  = threadIdx.x;
    int b  = blockIdx.x >> 9;               // Nn/4 = 512 blocks per batch
    int i0 = (blockIdx.x & 511) * 4;
    int w  = t >> 6, lane = t & 63;

    for (int i = t; i < 4 * C; i += 512)
        hi4[i / C][i % C] = h[((size_t)(b * Nn) + i0 + i / C) * C + (i % C)];
    if (t < 4) sqi[t] = sq[b * Nn + i0 + t];
    __syncthreads();

    // ---- dist phase (8 waves share the 2048 columns), fused sum/sumsq/min ----
    const float4* H0 = (const float4*)hi4[0];
    const float4* H1 = (const float4*)hi4[1];
    const float4* H2 = (const float4*)hi4[2];
    const float4* H3 = (const float4*)hi4[3];
    float ps0=0.f,ps1=0.f,ps2=0.f,ps3=0.f, pq0=0.f,pq1=0.f,pq2=0.f,pq3=0.f;
    float mn0=FLT_MAX,mn1=FLT_MAX,mn2=FLT_MAX,mn3=FLT_MAX;
    for (int j = t; j < Nn; j += 512){
        const float4* hj = (const float4*)(h + ((size_t)(b * Nn) + j) * C);
        float d0 = 0.f, d1 = 0.f, d2 = 0.f, d3 = 0.f;
#pragma unroll 4
        for (int c4 = 0; c4 < C / 4; c4++){
            float4 v = hj[c4];
            float4 a0 = H0[c4], a1 = H1[c4], a2 = H2[c4], a3 = H3[c4];
            d0 += a0.x*v.x + a0.y*v.y + a0.z*v.z + a0.w*v.w;
            d1 += a1.x*v.x + a1.y*v.y + a1.z*v.z + a1.w*v.w;
            d2 += a2.x*v.x + a2.y*v.y + a2.z*v.z + a2.w*v.w;
            d3 += a3.x*v.x + a3.y*v.y + a3.z*v.z + a3.w*v.w;
        }
        float sj = sq[b * Nn + j];
        float D0 = sqi[0] + sj - 2.f*d0; dist[0][j] = D0; ps0 += D0; pq0 += D0*D0; mn0 = fminf(mn0, D0);
        float D1 = sqi[1] + sj - 2.f*d1; dist[1][j] = D1; ps1 += D1; pq1 += D1*D1; mn1 = fminf(mn1, D1);
        float D2 = sqi[2] + sj - 2.f*d2; dist[2][j] = D2; ps2 += D2; pq2 += D2*D2; mn2 = fminf(mn2, D2);
        float D3 = sqi[3] + sj - 2.f*d3; dist[3][j] = D3; ps3 += D3; pq3 += D3*D3; mn3 = fminf(mn3, D3);
    }
#pragma unroll
    for (int d = 1; d < 64; d <<= 1){
        ps0 += __shfl_xor(ps0, d); pq0 += __shfl_xor(pq0, d); mn0 = fminf(mn0, __shfl_xor(mn0, d));
        ps1 += __shfl_xor(ps1, d); pq1 += __shfl_xor(pq1, d); mn1 = fminf(mn1, __shfl_xor(mn1, d));
        ps2 += __shfl_xor(ps2, d); pq2 += __shfl_xor(pq2, d); mn2 = fminf(mn2, __shfl_xor(mn2, d));
        ps3 += __shfl_xor(ps3, d); pq3 += __shfl_xor(pq3, d); mn3 = fminf(mn3, __shfl_xor(mn3, d));
    }
    if (lane == 0){
        statred[0][0][w] = ps0; statred[0][1][w] = pq0; statred[0][2][w] = mn0;
        statred[1][0][w] = ps1; statred[1][1][w] = pq1; statred[1][2][w] = mn1;
        statred[2][0][w] = ps2; statred[2][1][w] = pq2; statred[2][2][w] = mn2;
        statred[3][0][w] = ps3; statred[3][1][w] = pq3; statred[3][2][w] = mn3;
    }
    __syncthreads();

    // ---- select: waves (2*qq+half); wave owns slot rows [half*16, half*16+16) ----
    int qq = w >> 1, half = w & 1;
    const float* dw = dist[qq];
    int s0 = half * 16;

    float smu = 0.f, mnq = FLT_MAX;
#pragma unroll
    for (int i = 0; i < 8; i++){ smu += statred[qq][0][i]; mnq = fminf(mnq, statred[qq][2][i]); }
    float mu = smu * (1.f / (float)Nn);
    float span = fmaxf(mu - mnq, 0.f);

    float lo = mnq;  int clo = 0;
    float hi = FLT_MAX;  int chi = Nn;

    // seed sweep: 5 skew-adaptive pivots over this wave's 16 rows
    float PV[5] = { mnq + 0.25f*span, mnq + 0.40f*span, mnq + 0.55f*span,
                    mnq + 0.75f*span, mu };
    {
        int c0 = 0, c1 = 0, c2 = 0, c3 = 0, c4 = 0;
        for (int s8 = s0; s8 < s0 + 16; s8 += 8){
            float vv[8];
#pragma unroll
            for (int u = 0; u < 8; u++) vv[u] = dw[(s8 + u) * 64 + lane];
#pragma unroll
            for (int u = 0; u < 8; u++){
                float v = vv[u];
                c0 += (v < PV[0]) ? 1 : 0;
                c1 += (v < PV[1]) ? 1 : 0;
                c2 += (v < PV[2]) ? 1 : 0;
                c3 += (v < PV[3]) ? 1 : 0;
                c4 += (v < PV[4]) ? 1 : 0;
            }
        }
#pragma unroll
        for (int d = 1; d < 64; d <<= 1){
            c0 += __shfl_xor(c0, d);
            c1 += __shfl_xor(c1, d);
            c2 += __shfl_xor(c2, d);
            c3 += __shfl_xor(c3, d);
            c4 += __shfl_xor(c4, d);
        }
        if (lane == 0){
            cntred[qq][0][half] = c0; cntred[qq][1][half] = c1; cntred[qq][2][half] = c2;
            cntred[qq][3][half] = c3; cntred[qq][4][half] = c4;
        }
    }
    __syncthreads();
    {
        int CC[5];
#pragma unroll
        for (int pi = 0; pi < 5; pi++) CC[pi] = cntred[qq][pi][0] + cntred[qq][pi][1];
#pragma unroll
        for (int pi = 0; pi < 5; pi++){
            if (CC[pi] >= Kn){ if (PV[pi] < hi){ hi = PV[pi]; chi = CC[pi]; } }
            else             { if (PV[pi] > lo){ lo = PV[pi]; clo = CC[pi]; } }
        }
    }

    // refine: fixed 4 barrier-synced iterations (flags gate math)
    for (int it = 0; it < 4; it++){
        bool act = (chi > 128);
        float piv = 0.f;
        int c = 0;
        if (act){
            int den = (chi - clo) > 0 ? (chi - clo) : 1;
            piv = (it & 1) ? 0.5f * (lo + hi)
                           : lo + (hi - lo) * ((float)(96 - clo) / (float)den);
            if (!(piv > lo && piv < hi)) piv = 0.5f * (lo + hi);
            if (piv > lo && piv < hi){
                for (int s8 = s0; s8 < s0 + 16; s8 += 8){
                    float vv[8];
#pragma unroll
                    for (int u = 0; u < 8; u++) vv[u] = dw[(s8 + u) * 64 + lane];
#pragma unroll
                    for (int u = 0; u < 8; u++) c += (vv[u] < piv) ? 1 : 0;
                }
#pragma unroll
                for (int d = 1; d < 64; d <<= 1) c += __shfl_xor(c, d);
            } else act = false;
        }
        __syncthreads();
        if (lane == 0) cntred[qq][5][half] = c;
        __syncthreads();
        if (act){
            int ct = cntred[qq][5][0] + cntred[qq][5][1];
            if (ct >= Kn){ if (piv < hi){ hi = piv; chi = ct; } }
            else         { if (piv > lo){ lo = piv; clo = ct; } }
        }
    }

    size_t obase = ((size_t)(b * Nn) + i0 + qq) * Kn;
    bool ok = (chi <= 128);
    unsigned long long me_lower = (1ull << lane) - 1ull;

    // (A) count my half's candidates (for cross-half compact base)
    {
        int ch = 0;
        if (ok){
            for (int s8 = s0; s8 < s0 + 16; s8 += 8){
                float vv[8];
#pragma unroll
                for (int u = 0; u < 8; u++) vv[u] = dw[(s8 + u) * 64 + lane];
#pragma unroll
                for (int u = 0; u < 8; u++) ch += (vv[u] < hi) ? 1 : 0;
            }
#pragma unroll
            for (int d = 1; d < 64; d <<= 1) ch += __shfl_xor(ch, d);
        }
        __syncthreads();
        if (lane == 0) cntred[qq][5][half] = ch;
        keybuf[qq][half * 64 + lane] = ~0ull;     // pad
        __syncthreads();
    }
    // (B) compact (same slot order as 1-wave version: half0 rows 0-15, half1 16-31)
    {
        int boff = (half == 1) ? cntred[qq][5][0] : 0;
        if (ok){
            for (int s8 = s0; s8 < s0 + 16; s8 += 8){
                float vv[8];
#pragma unroll
                for (int u = 0; u < 8; u++) vv[u] = dw[(s8 + u) * 64 + lane];
#pragma unroll
                for (int u = 0; u < 8; u++){
                    bool cnd = vv[u] < hi;
                    unsigned long long m = __ballot(cnd);
                    if (cnd){
                        int o = boff + __popcll(m & me_lower);
                        if (o < 128)
                            keybuf[qq][o] = (((unsigned long long)enc_f(vv[u])) << 16) | (unsigned)((s8 + u) * 64 + lane);
                    }
                    boff += __popcll(m);
                }
            }
        }
        __syncthreads();
    }
    // (C) rank: one key per thread (position = half*64 + lane)
    if (ok){
        int pos = half * 64 + lane;
        unsigned long long k0 = keybuf[qq][pos];
        int r0 = 0;
        int nR = (chi + 7) & ~7;
        for (int j2 = 0; j2 < nR; j2 += 8){
            unsigned long long a0 = keybuf[qq][j2+0], a1 = keybuf[qq][j2+1];
            unsigned long long a2 = keybuf[qq][j2+2], a3 = keybuf[qq][j2+3];
            unsigned long long a4 = keybuf[qq][j2+4], a5 = keybuf[qq][j2+5];
            unsigned long long a6 = keybuf[qq][j2+6], a7 = keybuf[qq][j2+7];
            r0 += (a0<k0)+(a1<k0)+(a2<k0)+(a3<k0)+(a4<k0)+(a5<k0)+(a6<k0)+(a7<k0);
        }
        if (pos < chi && r0 < Kn) idxout[obase + r0] = (int)(k0 & 0xffffu);
    } else if (half == 0){
        // exact fallback (pathological ties only): barrier-free, half0 wave only
        unsigned selmask = 0u;
        for (int e = 0; e < Kn; e++){
            unsigned long long best = ~0ull;
#pragma unroll
            for (int s = 0; s < 32; s++){
                float v = dw[s * 64 + lane];
                if (v < hi && !((selmask >> s) & 1)){
                    unsigned long long key = (((unsigned long long)enc_f(v)) << 16) | (unsigned)(s * 64 + lane);
                    best = (key < best) ? key : best;
                }
            }
#pragma unroll
            for (int d = 1; d < 64; d <<= 1){
                unsigned long long ov = __shfl_xor(best, d);
                best = (ov < best) ? ov : best;
            }
            int jj = (int)(best & 0xffffu);
            if ((jj & 63) == lane) selmask |= 1u << (jj >> 6);
            if (lane == 0) idxout[obase + e] = jj;
        }
    }
}

// ---- pre1: p = x@(W1a-W1b)+b1, q = x@W1b  (layer-1 factorization) ----
__global__ __launch_bounds__(256) void pre1_kernel(const float* __restrict__ x,
        const float* __restrict__ w1, const float* __restrict__ b1,
        float* __restrict__ p, float* __restrict__ q){
    int t = threadIdx.x, w = t >> 6, c = t & 63;
    float wd[8], wb[8];
#pragma unroll
    for (int f = 0; f < 8; f++){
        float wbv = w1[(8 + f) * 64 + c];
        wb[f] = wbv;
        wd[f] = w1[f * 64 + c] - wbv;
    }
    float b1c = b1[c];
    int slot = blockIdx.x * 4 + w;                 // 2048 slots
    for (int it = 0; it < 16; it++){
        int node = slot + it * 2048;
        const float* xp = x + (size_t)node * Fin;
        float pv = b1c, qv = 0.f;
#pragma unroll
        for (int f = 0; f < 8; f++){
            float xv = xp[f];
            pv += xv * wd[f]; qv += xv * wb[f];
        }
        p[(size_t)node * 64 + c] = pv;
        q[(size_t)node * 64 + c] = qv;
    }
}

// ---- stats pass 1: moments of z1 = p[i]+q[j] over edges ----
__global__ __launch_bounds__(256) void stats1_kernel(const float* __restrict__ p, const float* __restrict__ q,
        const int* __restrict__ idx, float* __restrict__ sumP, float* __restrict__ ssqP){
    __shared__ float red[2][4][64];
    int t = threadIdx.x, w = t >> 6, c = t & 63;
    float s = 0.f, ss = 0.f;
    int slot = blockIdx.x * 4 + w;                 // 4096 slots
    for (int it = 0; it < 8; it++){
        int node = slot + it * 4096;
        int b = node >> 11;
        float pc = p[(size_t)node * 64 + c];
        const int* ip = idx + (size_t)node * Kn;
        for (int k = 0; k < Kn; k++){
            int j = ip[k];
            float z = pc + q[((size_t)(b << 11) + j) * 64 + c];
            s += z; ss += z * z;
        }
    }
    red[0][w][c] = s; red[1][w][c] = ss;
    __syncthreads();
    if (w == 0){
        sumP[blockIdx.x * 64 + c] = red[0][0][c] + red[0][1][c] + red[0][2][c] + red[0][3][c];
        ssqP[blockIdx.x * 64 + c] = red[1][0][c] + red[1][1][c] + red[1][2][c] + red[1][3][c];
    }
}

// ---- finalize BN params from partials ----
__global__ void finalize_kernel(const float* __restrict__ sumP, const float* __restrict__ ssqP,
        const float* __restrict__ gg, const float* __restrict__ bt,
        float* __restrict__ scale, float* __restrict__ shift, float inv_count){
    int c = threadIdx.x;   // 64 threads
    float s = 0.f, q = 0.f;
    for (int i = 0; i < NSTATB; i++){ s += sumP[i * 64 + c]; q += ssqP[i * 64 + c]; }
    float mu  = s * inv_count;
    float var = q * inv_count - mu * mu;
    float sc  = gg[c] / sqrtf(var + EPSV);
    scale[c] = sc;
    shift[c] = bt[c] - mu * sc;
}

// ---- stats pass 2: z1 -> bn1+relu -> z2 (f16 dot2), 2 edges per iteration ----
__global__ __launch_bounds__(256) void stats2_kernel(const float* __restrict__ p, const float* __restrict__ q,
        const int* __restrict__ idx,
        const float* __restrict__ sc1v, const float* __restrict__ sh1v,
        const float* __restrict__ w2, const float* __restrict__ b2,
        float* __restrict__ sumP, float* __restrict__ ssqP){
    __shared__ __align__(16) f16 hsh[4][2][64];
    __shared__ float red[2][4][64];
    int t = threadIdx.x, w = t >> 6, c = t & 63;
    f16x2 w2h[32];
#pragma unroll
    for (int f2 = 0; f2 < 32; f2++)
        w2h[f2] = f16x2{(f16)w2[(2*f2)*64 + c], (f16)w2[(2*f2+1)*64 + c]};
    float sc1 = sc1v[c], sh1 = sh1v[c], b2c = b2[c];
    float s = 0.f, ss = 0.f;
    int slot = blockIdx.x * 4 + w;
    for (int it = 0; it < 8; it++){
        int node = slot + it * 4096;
        int b = node >> 11;
        float pc = p[(size_t)node * 64 + c];
        const int* ip = idx + (size_t)node * Kn;
        for (int k = 0; k < Kn; k += 2){
            bool two = (k + 1 < Kn);
            int j0 = ip[k];
            int j1 = ip[two ? k + 1 : k];
            float za = pc + q[((size_t)(b << 11) + j0) * 64 + c];
            float zb = pc + q[((size_t)(b << 11) + j1) * 64 + c];
            hsh[w][0][c] = (f16)fmaxf(0.f, za * sc1 + sh1);
            hsh[w][1][c] = (f16)fmaxf(0.f, zb * sc1 + sh1);
            const uint4* h40 = (const uint4*)hsh[w][0];
            const uint4* h41 = (const uint4*)hsh[w][1];
            float p00=0.f,p01=0.f,p02=0.f,p03=0.f, p10=0.f,p11=0.f,p12=0.f,p13=0.f;
#pragma unroll
            for (int i = 0; i < 8; i++){
                uint4 u0 = h40[i], u1 = h41[i];
                p00 = __builtin_amdgcn_fdot2(__builtin_bit_cast(f16x2, u0.x), w2h[4*i+0], p00, false);
                p10 = __builtin_amdgcn_fdot2(__builtin_bit_cast(f16x2, u1.x), w2h[4*i+0], p10, false);
                p01 = __builtin_amdgcn_fdot2(__builtin_bit_cast(f16x2, u0.y), w2h[4*i+1], p01, false);
                p11 = __builtin_amdgcn_fdot2(__builtin_bit_cast(f16x2, u1.y), w2h[4*i+1], p11, false);
                p02 = __builtin_amdgcn_fdot2(__builtin_bit_cast(f16x2, u0.z), w2h[4*i+2], p02, false);
                p12 = __builtin_amdgcn_fdot2(__builtin_bit_cast(f16x2, u1.z), w2h[4*i+2], p12, false);
                p03 = __builtin_amdgcn_fdot2(__builtin_bit_cast(f16x2, u0.w), w2h[4*i+3], p03, false);
                p13 = __builtin_amdgcn_fdot2(__builtin_bit_cast(f16x2, u1.w), w2h[4*i+3], p13, false);
            }
            float z20 = b2c + ((p00 + p01) + (p02 + p03));
            float z21 = b2c + ((p10 + p11) + (p12 + p13));
            s += z20; ss += z20 * z20;
            if (two){ s += z21; ss += z21 * z21; }
        }
    }
    red[0][w][c] = s; red[1][w][c] = ss;
    __syncthreads();
    if (w == 0){
        sumP[blockIdx.x * 64 + c] = red[0][0][c] + red[0][1][c] + red[0][2][c] + red[0][3][c];
        ssqP[blockIdx.x * 64 + c] = red[1][0][c] + red[1][1][c] + red[1][2][c] + red[1][3][c];
    }
}

// ---- conv1: wave-per-node, 2 edges per iteration, f16 packed-dot2 layers 2/3 ----
__global__ __launch_bounds__(256) void conv1_kernel(const float* __restrict__ p, const float* __restrict__ q,
        const int* __restrict__ idx,
        const float* __restrict__ sc1v, const float* __restrict__ sh1v,
        const float* __restrict__ w2, const float* __restrict__ b2,
        const float* __restrict__ sc2v, const float* __restrict__ sh2v,
        const float* __restrict__ w3, const float* __restrict__ b3,
        float* __restrict__ x1){
    __shared__ __align__(16) f16 hA[4][2][64];
    __shared__ __align__(16) f16 hB[4][2][64];
    int t = threadIdx.x, w = t >> 6, c = t & 63;
    f16x2 w2h[32], w3h[32];
#pragma unroll
    for (int f2 = 0; f2 < 32; f2++){
        w2h[f2] = f16x2{(f16)w2[(2*f2)*64 + c], (f16)w2[(2*f2+1)*64 + c]};
        w3h[f2] = f16x2{(f16)w3[(2*f2)*64 + c], (f16)w3[(2*f2+1)*64 + c]};
    }
    float sc1 = sc1v[c], sh1 = sh1v[c], sc2 = sc2v[c], sh2 = sh2v[c];
    float b2c = b2[c], b3c = b3[c];
    int node = blockIdx.x * 4 + w;
    int b = node >> 11;
    float pc = p[(size_t)node * 64 + c];
    const int* ip = idx + (size_t)node * Kn;
    float acc = -FLT_MAX;
    for (int k = 0; k < Kn; k += 2){
        bool two = (k + 1 < Kn);
        int j0 = ip[k];
        int j1 = ip[two ? k + 1 : k];
        float za = pc + q[((size_t)(b << 11) + j0) * 64 + c];
        float zb = pc + q[((size_t)(b << 11) + j1) * 64 + c];
        hA[w][0][c] = (f16)fmaxf(0.f, za * sc1 + sh1);
        hA[w][1][c] = (f16)fmaxf(0.f, zb * sc1 + sh1);
        const uint4* h40 = (const uint4*)hA[w][0];
        const uint4* h41 = (const uint4*)hA[w][1];
        float p00=0.f,p01=0.f,p02=0.f,p03=0.f, p10=0.f,p11=0.f,p12=0.f,p13=0.f;
#pragma unroll
        for (int i = 0; i < 8; i++){
            uint4 u0 = h40[i], u1 = h41[i];
            p00 = __builtin_amdgcn_fdot2(__builtin_bit_cast(f16x2, u0.x), w2h[4*i+0], p00, false);
            p10 = __builtin_amdgcn_fdot2(__builtin_bit_cast(f16x2, u1.x), w2h[4*i+0], p10, false);
            p01 = __builtin_amdgcn_fdot2(__builtin_bit_cast(f16x2, u0.y), w2h[4*i+1], p01, false);
            p11 = __builtin_amdgcn_fdot2(__builtin_bit_cast(f16x2, u1.y), w2h[4*i+1], p11, false);
            p02 = __builtin_amdgcn_fdot2(__builtin_bit_cast(f16x2, u0.z), w2h[4*i+2], p02, false);
            p12 = __builtin_amdgcn_fdot2(__builtin_bit_cast(f16x2, u1.z), w2h[4*i+2], p12, false);
            p03 = __builtin_amdgcn_fdot2(__builtin_bit_cast(f16x2, u0.w), w2h[4*i+3], p03, false);
            p13 = __builtin_amdgcn_fdot2(__builtin_bit_cast(f16x2, u1.w), w2h[4*i+3], p13, false);
        }
        float z20 = b2c + ((p00 + p01) + (p02 + p03));
        float z21 = b2c + ((p10 + p11) + (p12 + p13));
        hB[w][0][c] = (f16)fmaxf(0.f, z20 * sc2 + sh2);
        hB[w][1][c] = (f16)fmaxf(0.f, z21 * sc2 + sh2);
        const uint4* g40 = (const uint4*)hB[w][0];
        const uint4* g41 = (const uint4*)hB[w][1];
        float q00=0.f,q01=0.f,q02=0.f,q03=0.f, q10=0.f,q11=0.f,q12=0.f,q13=0.f;
#pragma unroll
        for (int i = 0; i < 8; i++){
            uint4 u0 = g40[i], u1 = g41[i];
            q00 = __builtin_amdgcn_fdot2(__builtin_bit_cast(f16x2, u0.x), w3h[4*i+0], q00, false);
            q10 = __builtin_amdgcn_fdot2(__builtin_bit_cast(f16x2, u1.x), w3h[4*i+0], q10, false);
            q01 = __builtin_amdgcn_fdot2(__builtin_bit_cast(f16x2, u0.y), w3h[4*i+1], q01, false);
            q11 = __builtin_amdgcn_fdot2(__builtin_bit_cast(f16x2, u1.y), w3h[4*i+1], q11, false);
            q02 = __builtin_amdgcn_fdot2(__builtin_bit_cast(f16x2, u0.z), w3h[4*i+2], q02, false);
            q12 = __builtin_amdgcn_fdot2(__builtin_bit_cast(f16x2, u1.z), w3h[4*i+2], q12, false);
            q03 = __builtin_amdgcn_fdot2(__builtin_bit_cast(f16x2, u0.w), w3h[4*i+3], q03, false);
            q13 = __builtin_amdgcn_fdot2(__builtin_bit_cast(f16x2, u1.w), w3h[4*i+3], q13, false);
        }
        float z30 = b3c + ((q00 + q01) + (q02 + q03));
        float z31 = b3c + ((q10 + q11) + (q12 + q13));
        acc = fmaxf(acc, z30);
        if (two) acc = fmaxf(acc, z31);
    }
    x1[(size_t)node * 64 + c] = acc;
}

// ---- pre2: u = x1@(W4a-W4b)+b4 (into x2 buffer), v = x1@W4b ----
__global__ __launch_bounds__(256) void pre2_kernel(const float* __restrict__ x1,
        const float* __restrict__ w4, const float* __restrict__ b4,
        float* __restrict__ u, float* __restrict__ v){
    __shared__ float x1s[16][64];
    int t = threadIdx.x;
    int c = t & 127, h = t >> 7;
    float wd[64], wb[64];
#pragma unroll
    for (int f = 0; f < 64; f++){
        float wbv = w4[(64 + f) * 128 + c];
        wb[f] = wbv;
        wd[f] = w4[f * 128 + c] - wbv;
    }
    float b4c = b4[c];
    int base = blockIdx.x * 16;
    for (int i = t; i < 16 * 64; i += 256)
        x1s[i >> 6][i & 63] = x1[(size_t)(base + (i >> 6)) * 64 + (i & 63)];
    __syncthreads();
    for (int n = 0; n < 8; n++){
        int node = base + h * 8 + n;
        const float4* xr = (const float4*)x1s[h * 8 + n];
        float u0 = 0.f, u1 = 0.f, v0 = 0.f, v1 = 0.f;
#pragma unroll
        for (int f4 = 0; f4 < 16; f4++){
            float4 xv = xr[f4];
            float pa = xv.x * wd[4*f4] + xv.y * wd[4*f4+1] + xv.z * wd[4*f4+2] + xv.w * wd[4*f4+3];
            float pb = xv.x * wb[4*f4] + xv.y * wb[4*f4+1] + xv.z * wb[4*f4+2] + xv.w * wb[4*f4+3];
            if (f4 & 1){ u1 += pa; v1 += pb; } else { u0 += pa; v0 += pb; }
        }
        u[(size_t)node * 128 + c] = b4c + u0 + u1;
        v[(size_t)node * 128 + c] = v0 + v1;
    }
}

// ---- gmax2: x2[i][c] = u[i][c] + max_k v[j_k][c]  (x2 holds u on entry) ----
__global__ __launch_bounds__(256) void gmax2_kernel(const float* __restrict__ v, const int* __restrict__ idx,
        float* __restrict__ x2){
    int t = threadIdx.x, g = t >> 7, c = t & 127;
    int node = blockIdx.x * 2 + g;
    int b = node >> 11;
    const int* ip = idx + (size_t)node * Kn;
    float vm = -FLT_MAX;
    for (int k = 0; k < Kn; k++){
        int j = ip[k];
        vm = fmaxf(vm, v[((size_t)(b << 11) + j) * 128 + c]);
    }
    x2[(size_t)node * 128 + c] += vm;
}

// ---- out = cat(x1,x2) @ w5 + b5, global max over nodes (encoded atomics) ----
__global__ __launch_bounds__(256) void outpool_kernel(const float* __restrict__ x1, const float* __restrict__ x2,
        const float* __restrict__ w5, const float* __restrict__ b5, unsigned* __restrict__ pooled){
    __shared__ float rows[8][192];
    int t = threadIdx.x;
    int node0 = blockIdx.x * 8;
    for (int i = t; i < 8 * 192; i += 256){
        int e = i / 192, f = i - e * 192;
        int nd = node0 + e;
        rows[e][f] = (f < 64) ? x1[(size_t)nd * 64 + f] : x2[(size_t)nd * 128 + f - 64];
    }
    __syncthreads();
    float z[8];
#pragma unroll
    for (int e = 0; e < 8; e++) z[e] = b5[t];
    for (int f = 0; f < 192; f++){
        float w = w5[f * 256 + t];
#pragma unroll
        for (int e = 0; e < 8; e++) z[e] += rows[e][f] * w;
    }
    float m = z[0];
#pragma unroll
    for (int e = 1; e < 8; e++) m = fmaxf(m, z[e]);
    int b = node0 >> 11;
    atomicMax(&pooled[b * 256 + t], enc_f(m));
}

// ---- head: decode pooled, MLP [256,128,64,4] with training-mode BN over 16 ----
__global__ __launch_bounds__(256) void head_kernel(const unsigned* __restrict__ pooledE,
        const float* __restrict__ w6, const float* __restrict__ b6, const float* __restrict__ g6, const float* __restrict__ bt6,
        const float* __restrict__ w7, const float* __restrict__ b7, const float* __restrict__ g7, const float* __restrict__ bt7,
        const float* __restrict__ w8, const float* __restrict__ b8, float* __restrict__ out){
    __shared__ float P[16][256];
    __shared__ float H6[16][128];
    __shared__ float H7[16][64];
    int t = threadIdx.x;
    for (int i = t; i < 16 * 256; i += 256) P[i >> 8][i & 255] = dec_f(pooledE[i]);
    __syncthreads();
    for (int i = t; i < 16 * 128; i += 256){
        int r = i >> 7, c = i & 127;
        float z = b6[c];
        for (int f = 0; f < 256; f++) z += P[r][f] * w6[f * 128 + c];
        H6[r][c] = z;
    }
    __syncthreads();
    if (t < 128){
        float s = 0.f, q = 0.f;
        for (int r = 0; r < 16; r++){ float v = H6[r][t]; s += v; q += v * v; }
        float mu = s * (1.f / 16.f);
        float var = q * (1.f / 16.f) - mu * mu;
        float sc = g6[t] / sqrtf(var + EPSV);
        float sh = bt6[t] - mu * sc;
        for (int r = 0; r < 16; r++) H6[r][t] = fmaxf(0.f, H6[r][t] * sc + sh);
    }
    __syncthreads();
    for (int i = t; i < 16 * 64; i += 256){
        int r = i >> 6, c = i & 63;
        float z = b7[c];
        for (int f = 0; f < 128; f++) z += H6[r][f] * w7[f * 64 + c];
        H7[r][c] = z;
    }
    __syncthreads();
    if (t < 64){
        float s = 0.f, q = 0.f;
        for (int r = 0; r < 16; r++){ float v = H7[r][t]; s += v; q += v * v; }
        float mu = s * (1.f / 16.f);
        float var = q * (1.f / 16.f) - mu * mu;
        float sc = g7[t] / sqrtf(var + EPSV);
        float sh = bt7[t] - mu * sc;
        for (int r = 0; r < 16; r++) H7[r][t] = fmaxf(0.f, H7[r][t] * sc + sh);
    }
    __syncthreads();
    if (t < 64){
        int r = t >> 2, c = t & 3;
        float z = b8[c];
        for (int f = 0; f < 64; f++) z += H7[r][f] * w8[f * 4 + c];
        out[t] = z;
    }
}

extern "C" void kernel_launch(void* const* d_in, const int* in_sizes, int n_in,
                              void* d_out, int out_size, void* d_ws, size_t ws_size,
                              hipStream_t stream){
    const float* x   = (const float*)d_in[0];
    const float* w1  = (const float*)d_in[1];
    const float* b1  = (const float*)d_in[2];
    const float* g1  = (const float*)d_in[3];
    const float* bt1 = (const float*)d_in[4];
    const float* w2  = (const float*)d_in[5];
    const float* b2  = (const float*)d_in[6];
    const float* g2  = (const float*)d_in[7];
    const float* bt2 = (const float*)d_in[8];
    const float* w3  = (const float*)d_in[9];
    const float* b3  = (const float*)d_in[10];
    const float* w4  = (const float*)d_in[11];
    const float* b4  = (const float*)d_in[12];
    const float* w5  = (const float*)d_in[13];
    const float* b5  = (const float*)d_in[14];
    const float* w6  = (const float*)d_in[15];
    const float* b6  = (const float*)d_in[16];
    const float* g6  = (const float*)d_in[17];
    const float* bt6 = (const float*)d_in[18];
    const float* w7  = (const float*)d_in[19];
    const float* b7  = (const float*)d_in[20];
    const float* g7  = (const float*)d_in[21];
    const float* bt7 = (const float*)d_in[22];
    const float* w8  = (const float*)d_in[23];
    const float* b8  = (const float*)d_in[24];
    float* out = (float*)d_out;

    char* ws = (char*)d_ws;
    size_t off = 0;
    auto alloc = [&](size_t bytes)->char*{
        char* p = ws + off;
        off += (bytes + 255) & ~(size_t)255;
        return p;
    };
    int*      idx1   = (int*)alloc((size_t)EDG * 4);
    int*      idx2   = (int*)alloc((size_t)EDG * 4);
    float*    sq1    = (float*)alloc((size_t)NODES * 4);
    float*    sq2    = (float*)alloc((size_t)NODES * 4);
    float*    x1     = (float*)alloc((size_t)NODES * 64 * 4);
    float*    x2     = (float*)alloc((size_t)NODES * 128 * 4);
    float*    sumP   = (float*)alloc((size_t)NSTATB * 64 * 4);
    float*    ssqP   = (float*)alloc((size_t)NSTATB * 64 * 4);
    float*    scale1 = (float*)alloc(64 * 4);
    float*    shift1 = (float*)alloc(64 * 4);
    float*    scale2 = (float*)alloc(64 * 4);
    float*    shift2 = (float*)alloc(64 * 4);
    unsigned* pooled = (unsigned*)alloc((size_t)Bn * 256 * 4);
    float*    p      = (float*)alloc((size_t)NODES * 64 * 4);
    float*    q      = (float*)alloc((size_t)NODES * 64 * 4);
    float*    v      = p;   // overlay: p,q are dead once conv1 finishes; v = 128 floats/node spans p+q

    hipMemsetAsync(pooled, 0, (size_t)Bn * 256 * 4, stream);

    sq_kernel<8><<<(NODES + 255) / 256, 256, 0, stream>>>(x, sq1);
    knn_kernel<8><<<NODES / 4, 512, 0, stream>>>(x, sq1, idx1);
    pre1_kernel<<<512, 256, 0, stream>>>(x, w1, b1, p, q);
    stats1_kernel<<<NSTATB, 256, 0, stream>>>(p, q, idx1, sumP, ssqP);
    finalize_kernel<<<1, 64, 0, stream>>>(sumP, ssqP, g1, bt1, scale1, shift1, 1.0f / (float)EDG);
    stats2_kernel<<<NSTATB, 256, 0, stream>>>(p, q, idx1, scale1, shift1, w2, b2, sumP, ssqP);
    finalize_kernel<<<1, 64, 0, stream>>>(sumP, ssqP, g2, bt2, scale2, shift2, 1.0f / (float)EDG);
    conv1_kernel<<<NODES / 4, 256, 0, stream>>>(p, q, idx1, scale1, shift1,
                                                w2, b2, scale2, shift2, w3, b3, x1);
    sq_kernel<64><<<(NODES + 255) / 256, 256, 0, stream>>>(x1, sq2);
    knn_kernel<64><<<NODES / 4, 512, 0, stream>>>(x1, sq2, idx2);
    pre2_kernel<<<NODES / 16, 256, 0, stream>>>(x1, w4, b4, x2, v);
    gmax2_kernel<<<NODES / 2, 256, 0, stream>>>(v, idx2, x2);
    outpool_kernel<<<NODES / 8, 256, 0, stream>>>(x1, x2, w5, b5, pooled);
    head_kernel<<<1, 256, 0, stream>>>(pooled, w6, b6, g6, bt6, w7, b7, g7, bt7, w8, b8, out);
}

// Round 19
// 1320.207 us; speedup vs baseline: 1.0505x; 1.0505x over previous
//
#include <hip/hip_runtime.h>
#include <cfloat>
#include <cstdint>

// Problem constants
constexpr int Bn   = 16;
constexpr int Nn   = 2048;
constexpr int Fin  = 8;
constexpr int Kn   = 35;
constexpr int NODES = Bn * Nn;          // 32768
constexpr int EDG   = NODES * Kn;       // 1146880
constexpr int NSTATB = 1024;            // stats grid blocks
constexpr float EPSV = 1e-5f;

typedef _Float16 f16;
typedef _Float16 f16x2 __attribute__((ext_vector_type(2)));

// ---- monotone float<->u32 encoding for ordered compare / atomic max ----
__device__ __forceinline__ unsigned enc_f(float f){
    unsigned u = __float_as_uint(f);
    return (u & 0x80000000u) ? ~u : (u | 0x80000000u);
}
__device__ __forceinline__ float dec_f(unsigned e){
    unsigned u = (e & 0x80000000u) ? (e ^ 0x80000000u) : ~e;
    return __uint_as_float(u);
}

// ---- squared norms per node ----
template<int C>
__global__ __launch_bounds__(256) void sq_kernel(const float* __restrict__ h, float* __restrict__ sq){
    int i = blockIdx.x * 256 + threadIdx.x;
    if (i >= NODES) return;
    const float* p = h + (size_t)i * C;
    float s = 0.f;
#pragma unroll
    for (int c = 0; c < C; c++) s += p[c] * p[c];
    sq[i] = s;
}

// ---- kNN: 4 queries per block, 256 threads (r18's 512-thread variant was flat
// on time with added outlier risk -> reverted). Dist fuses sum/sumsq/min stats;
// skew-adaptive pivots. Select tail slimmed: refine to chi<=64, 64-slot keybuf,
// single-key rank with b128 (ulonglong2) LDS reads. Exact top_k set semantics.
template<int C>
__global__ __launch_bounds__(256) void knn_kernel(const float* __restrict__ h, const float* __restrict__ sq,
                                                  int* __restrict__ idxout){
    __shared__ float dist[4][Nn];                  // 32 KB
    __shared__ float hi4[4][C];
    __shared__ float sqi[4];
    __shared__ float statred[4][3][4];             // [query][sum|ssq|min][wave]
    __shared__ __align__(16) unsigned long long keybuf[4][64];  // 2 KB candidate keys
    int t  = threadIdx.x;
    int b  = blockIdx.x >> 9;               // Nn/4 = 512 blocks per batch
    int i0 = (blockIdx.x & 511) * 4;
    int w  = t >> 6, lane = t & 63;

    for (int i = t; i < 4 * C; i += 256)
        hi4[i / C][i % C] = h[((size_t)(b * Nn) + i0 + i / C) * C + (i % C)];
    if (t < 4) sqi[t] = sq[b * Nn + i0 + t];
    __syncthreads();

    // ---- dist phase with fused per-query sum/sumsq/min partials ----
    const float4* H0 = (const float4*)hi4[0];
    const float4* H1 = (const float4*)hi4[1];
    const float4* H2 = (const float4*)hi4[2];
    const float4* H3 = (const float4*)hi4[3];
    float ps0=0.f,ps1=0.f,ps2=0.f,ps3=0.f, pq0=0.f,pq1=0.f,pq2=0.f,pq3=0.f;
    float mn0=FLT_MAX,mn1=FLT_MAX,mn2=FLT_MAX,mn3=FLT_MAX;
    for (int j = t; j < Nn; j += 256){
        const float4* hj = (const float4*)(h + ((size_t)(b * Nn) + j) * C);
        float d0 = 0.f, d1 = 0.f, d2 = 0.f, d3 = 0.f;
#pragma unroll 4
        for (int c4 = 0; c4 < C / 4; c4++){
            float4 v = hj[c4];
            float4 a0 = H0[c4], a1 = H1[c4], a2 = H2[c4], a3 = H3[c4];
            d0 += a0.x*v.x + a0.y*v.y + a0.z*v.z + a0.w*v.w;
            d1 += a1.x*v.x + a1.y*v.y + a1.z*v.z + a1.w*v.w;
            d2 += a2.x*v.x + a2.y*v.y + a2.z*v.z + a2.w*v.w;
            d3 += a3.x*v.x + a3.y*v.y + a3.z*v.z + a3.w*v.w;
        }
        float sj = sq[b * Nn + j];
        float D0 = sqi[0] + sj - 2.f*d0; dist[0][j] = D0; ps0 += D0; pq0 += D0*D0; mn0 = fminf(mn0, D0);
        float D1 = sqi[1] + sj - 2.f*d1; dist[1][j] = D1; ps1 += D1; pq1 += D1*D1; mn1 = fminf(mn1, D1);
        float D2 = sqi[2] + sj - 2.f*d2; dist[2][j] = D2; ps2 += D2; pq2 += D2*D2; mn2 = fminf(mn2, D2);
        float D3 = sqi[3] + sj - 2.f*d3; dist[3][j] = D3; ps3 += D3; pq3 += D3*D3; mn3 = fminf(mn3, D3);
    }
#pragma unroll
    for (int d = 1; d < 64; d <<= 1){
        ps0 += __shfl_xor(ps0, d); pq0 += __shfl_xor(pq0, d); mn0 = fminf(mn0, __shfl_xor(mn0, d));
        ps1 += __shfl_xor(ps1, d); pq1 += __shfl_xor(pq1, d); mn1 = fminf(mn1, __shfl_xor(mn1, d));
        ps2 += __shfl_xor(ps2, d); pq2 += __shfl_xor(pq2, d); mn2 = fminf(mn2, __shfl_xor(mn2, d));
        ps3 += __shfl_xor(ps3, d); pq3 += __shfl_xor(pq3, d); mn3 = fminf(mn3, __shfl_xor(mn3, d));
    }
    if (lane == 0){
        statred[0][0][w] = ps0; statred[0][1][w] = pq0; statred[0][2][w] = mn0;
        statred[1][0][w] = ps1; statred[1][1][w] = pq1; statred[1][2][w] = mn1;
        statred[2][0][w] = ps2; statred[2][1][w] = pq2; statred[2][2][w] = mn2;
        statred[3][0][w] = ps3; statred[3][1][w] = pq3; statred[3][2][w] = mn3;
    }
    __syncthreads();

    // ---- per-wave select: wave w handles query i0+w ----
    const float* dw = dist[w];
    float smu = statred[w][0][0] + statred[w][0][1] + statred[w][0][2] + statred[w][0][3];
    float mnq = fminf(fminf(statred[w][2][0], statred[w][2][1]),
                      fminf(statred[w][2][2], statred[w][2][3]));
    float mu = smu * (1.f / (float)Nn);
    float span = fmaxf(mu - mnq, 0.f);

    float lo = mnq;  int clo = 0;   // count(< lmin) == 0 exactly
    float hi = FLT_MAX;  int chi = Nn;

    // seed sweep: 5 pivots as fractions of [lmin, mu] (skew-adaptive)
    float PV[5] = { mnq + 0.25f*span, mnq + 0.40f*span, mnq + 0.55f*span,
                    mnq + 0.75f*span, mu };
    int c0 = 0, c1 = 0, c2 = 0, c3 = 0, c4 = 0;
    for (int s8 = 0; s8 < 32; s8 += 8){
        float vv[8];
#pragma unroll
        for (int u = 0; u < 8; u++) vv[u] = dw[(s8 + u) * 64 + lane];
#pragma unroll
        for (int u = 0; u < 8; u++){
            float v = vv[u];
            c0 += (v < PV[0]) ? 1 : 0;
            c1 += (v < PV[1]) ? 1 : 0;
            c2 += (v < PV[2]) ? 1 : 0;
            c3 += (v < PV[3]) ? 1 : 0;
            c4 += (v < PV[4]) ? 1 : 0;
        }
    }
#pragma unroll
    for (int d = 1; d < 64; d <<= 1){
        c0 += __shfl_xor(c0, d);
        c1 += __shfl_xor(c1, d);
        c2 += __shfl_xor(c2, d);
        c3 += __shfl_xor(c3, d);
        c4 += __shfl_xor(c4, d);
    }
    {
        int CC[5] = {c0, c1, c2, c3, c4};
#pragma unroll
        for (int pi = 0; pi < 5; pi++){
            if (CC[pi] >= Kn){ if (PV[pi] < hi){ hi = PV[pi]; chi = CC[pi]; } }
            else             { if (PV[pi] > lo){ lo = PV[pi]; clo = CC[pi]; } }
        }
    }

    // refine until chi <= 64 (typically 0-2 iterations): ballot-free counting
    for (int it = 0; it < 24 && chi > 64; it++){
        int den = (chi - clo) > 0 ? (chi - clo) : 1;
        float piv = (it & 1) ? 0.5f * (lo + hi)
                             : lo + (hi - lo) * ((float)(48 - clo) / (float)den);
        if (!(piv > lo && piv < hi)) piv = 0.5f * (lo + hi);
        if (!(piv > lo && piv < hi)) break;   // ulp-collapsed: fallback handles
        int c = 0;
        for (int s8 = 0; s8 < 32; s8 += 8){
            float vv[8];
#pragma unroll
            for (int u = 0; u < 8; u++) vv[u] = dw[(s8 + u) * 64 + lane];
#pragma unroll
            for (int u = 0; u < 8; u++) c += (vv[u] < piv) ? 1 : 0;
        }
#pragma unroll
        for (int d = 1; d < 64; d <<= 1) c += __shfl_xor(c, d);
        if (c >= Kn){ hi = piv; chi = c; } else { lo = piv; clo = c; }
    }

    size_t obase = ((size_t)(b * Nn) + i0 + w) * Kn;

    if (chi <= 64){
        // compact all candidates (< hi) into 64-slot keybuf via ballot offsets
        keybuf[w][lane] = ~0ull;
        unsigned long long me_lower = (1ull << lane) - 1ull;
        int boff = 0;
        for (int s8 = 0; s8 < 32; s8 += 8){
            float vv[8];
#pragma unroll
            for (int u = 0; u < 8; u++) vv[u] = dw[(s8 + u) * 64 + lane];
#pragma unroll
            for (int u = 0; u < 8; u++){
                bool cnd = vv[u] < hi;
                unsigned long long m = __ballot(cnd);
                if (cnd){
                    int o = boff + __popcll(m & me_lower);
                    keybuf[w][o] = (((unsigned long long)enc_f(vv[u])) << 16) | (unsigned)((s8 + u) * 64 + lane);
                }
                boff += __popcll(m);
            }
        }
        // rank one key per lane against all chi keys via b128 LDS reads
        unsigned long long k0 = keybuf[w][lane];
        int r0 = 0;
        int nR = (chi + 7) & ~7;          // <= 64; padding keys are ~0ull
        const ulonglong2* kb2 = (const ulonglong2*)keybuf[w];
        for (int j2 = 0; j2 < nR; j2 += 8){
            ulonglong2 A = kb2[(j2 >> 1) + 0];
            ulonglong2 B = kb2[(j2 >> 1) + 1];
            ulonglong2 Cx = kb2[(j2 >> 1) + 2];
            ulonglong2 D = kb2[(j2 >> 1) + 3];
            r0 += (A.x<k0)+(A.y<k0)+(B.x<k0)+(B.y<k0)+(Cx.x<k0)+(Cx.y<k0)+(D.x<k0)+(D.y<k0);
        }
        if (lane < chi && r0 < Kn) idxout[obase + r0] = (int)(k0 & 0xffffu);
    } else {
        // exact fallback (pathological ties only): iterative wave-min extraction
        unsigned selmask = 0u;
        for (int e = 0; e < Kn; e++){
            unsigned long long best = ~0ull;
#pragma unroll
            for (int s = 0; s < 32; s++){
                float v = dw[s * 64 + lane];
                if (v < hi && !((selmask >> s) & 1)){
                    unsigned long long key = (((unsigned long long)enc_f(v)) << 16) | (unsigned)(s * 64 + lane);
                    best = (key < best) ? key : best;
                }
            }
#pragma unroll
            for (int d = 1; d < 64; d <<= 1){
                unsigned long long ov = __shfl_xor(best, d);
                best = (ov < best) ? ov : best;
            }
            int jj = (int)(best & 0xffffu);
            if ((jj & 63) == lane) selmask |= 1u << (jj >> 6);
            if (lane == 0) idxout[obase + e] = jj;
        }
    }
}

// ---- pre1: p = x@(W1a-W1b)+b1, q = x@W1b  (layer-1 factorization) ----
__global__ __launch_bounds__(256) void pre1_kernel(const float* __restrict__ x,
        const float* __restrict__ w1, const float* __restrict__ b1,
        float* __restrict__ p, float* __restrict__ q){
    int t = threadIdx.x, w = t >> 6, c = t & 63;
    float wd[8], wb[8];
#pragma unroll
    for (int f = 0; f < 8; f++){
        float wbv = w1[(8 + f) * 64 + c];
        wb[f] = wbv;
        wd[f] = w1[f * 64 + c] - wbv;
    }
    float b1c = b1[c];
    int slot = blockIdx.x * 4 + w;                 // 2048 slots
    for (int it = 0; it < 16; it++){
        int node = slot + it * 2048;
        const float* xp = x + (size_t)node * Fin;
        float pv = b1c, qv = 0.f;
#pragma unroll
        for (int f = 0; f < 8; f++){
            float xv = xp[f];
            pv += xv * wd[f]; qv += xv * wb[f];
        }
        p[(size_t)node * 64 + c] = pv;
        q[(size_t)node * 64 + c] = qv;
    }
}

// ---- stats pass 1: moments of z1 = p[i]+q[j] over edges ----
__global__ __launch_bounds__(256) void stats1_kernel(const float* __restrict__ p, const float* __restrict__ q,
        const int* __restrict__ idx, float* __restrict__ sumP, float* __restrict__ ssqP){
    __shared__ float red[2][4][64];
    int t = threadIdx.x, w = t >> 6, c = t & 63;
    float s = 0.f, ss = 0.f;
    int slot = blockIdx.x * 4 + w;                 // 4096 slots
    for (int it = 0; it < 8; it++){
        int node = slot + it * 4096;
        int b = node >> 11;
        float pc = p[(size_t)node * 64 + c];
        const int* ip = idx + (size_t)node * Kn;
        for (int k = 0; k < Kn; k++){
            int j = ip[k];
            float z = pc + q[((size_t)(b << 11) + j) * 64 + c];
            s += z; ss += z * z;
        }
    }
    red[0][w][c] = s; red[1][w][c] = ss;
    __syncthreads();
    if (w == 0){
        sumP[blockIdx.x * 64 + c] = red[0][0][c] + red[0][1][c] + red[0][2][c] + red[0][3][c];
        ssqP[blockIdx.x * 64 + c] = red[1][0][c] + red[1][1][c] + red[1][2][c] + red[1][3][c];
    }
}

// ---- finalize BN params from partials ----
__global__ void finalize_kernel(const float* __restrict__ sumP, const float* __restrict__ ssqP,
        const float* __restrict__ gg, const float* __restrict__ bt,
        float* __restrict__ scale, float* __restrict__ shift, float inv_count){
    int c = threadIdx.x;   // 64 threads
    float s = 0.f, q = 0.f;
    for (int i = 0; i < NSTATB; i++){ s += sumP[i * 64 + c]; q += ssqP[i * 64 + c]; }
    float mu  = s * inv_count;
    float var = q * inv_count - mu * mu;
    float sc  = gg[c] / sqrtf(var + EPSV);
    scale[c] = sc;
    shift[c] = bt[c] - mu * sc;
}

// ---- stats pass 2: z1 -> bn1+relu -> z2 (f16 dot2), 2 edges per iteration ----
__global__ __launch_bounds__(256) void stats2_kernel(const float* __restrict__ p, const float* __restrict__ q,
        const int* __restrict__ idx,
        const float* __restrict__ sc1v, const float* __restrict__ sh1v,
        const float* __restrict__ w2, const float* __restrict__ b2,
        float* __restrict__ sumP, float* __restrict__ ssqP){
    __shared__ __align__(16) f16 hsh[4][2][64];
    __shared__ float red[2][4][64];
    int t = threadIdx.x, w = t >> 6, c = t & 63;
    f16x2 w2h[32];
#pragma unroll
    for (int f2 = 0; f2 < 32; f2++)
        w2h[f2] = f16x2{(f16)w2[(2*f2)*64 + c], (f16)w2[(2*f2+1)*64 + c]};
    float sc1 = sc1v[c], sh1 = sh1v[c], b2c = b2[c];
    float s = 0.f, ss = 0.f;
    int slot = blockIdx.x * 4 + w;
    for (int it = 0; it < 8; it++){
        int node = slot + it * 4096;
        int b = node >> 11;
        float pc = p[(size_t)node * 64 + c];
        const int* ip = idx + (size_t)node * Kn;
        for (int k = 0; k < Kn; k += 2){
            bool two = (k + 1 < Kn);
            int j0 = ip[k];
            int j1 = ip[two ? k + 1 : k];
            float za = pc + q[((size_t)(b << 11) + j0) * 64 + c];
            float zb = pc + q[((size_t)(b << 11) + j1) * 64 + c];
            hsh[w][0][c] = (f16)fmaxf(0.f, za * sc1 + sh1);
            hsh[w][1][c] = (f16)fmaxf(0.f, zb * sc1 + sh1);
            const uint4* h40 = (const uint4*)hsh[w][0];
            const uint4* h41 = (const uint4*)hsh[w][1];
            float p00=0.f,p01=0.f,p02=0.f,p03=0.f, p10=0.f,p11=0.f,p12=0.f,p13=0.f;
#pragma unroll
            for (int i = 0; i < 8; i++){
                uint4 u0 = h40[i], u1 = h41[i];
                p00 = __builtin_amdgcn_fdot2(__builtin_bit_cast(f16x2, u0.x), w2h[4*i+0], p00, false);
                p10 = __builtin_amdgcn_fdot2(__builtin_bit_cast(f16x2, u1.x), w2h[4*i+0], p10, false);
                p01 = __builtin_amdgcn_fdot2(__builtin_bit_cast(f16x2, u0.y), w2h[4*i+1], p01, false);
                p11 = __builtin_amdgcn_fdot2(__builtin_bit_cast(f16x2, u1.y), w2h[4*i+1], p11, false);
                p02 = __builtin_amdgcn_fdot2(__builtin_bit_cast(f16x2, u0.z), w2h[4*i+2], p02, false);
                p12 = __builtin_amdgcn_fdot2(__builtin_bit_cast(f16x2, u1.z), w2h[4*i+2], p12, false);
                p03 = __builtin_amdgcn_fdot2(__builtin_bit_cast(f16x2, u0.w), w2h[4*i+3], p03, false);
                p13 = __builtin_amdgcn_fdot2(__builtin_bit_cast(f16x2, u1.w), w2h[4*i+3], p13, false);
            }
            float z20 = b2c + ((p00 + p01) + (p02 + p03));
            float z21 = b2c + ((p10 + p11) + (p12 + p13));
            s += z20; ss += z20 * z20;
            if (two){ s += z21; ss += z21 * z21; }
        }
    }
    red[0][w][c] = s; red[1][w][c] = ss;
    __syncthreads();
    if (w == 0){
        sumP[blockIdx.x * 64 + c] = red[0][0][c] + red[0][1][c] + red[0][2][c] + red[0][3][c];
        ssqP[blockIdx.x * 64 + c] = red[1][0][c] + red[1][1][c] + red[1][2][c] + red[1][3][c];
    }
}

// ---- conv1: wave-per-node, 2 edges per iteration, f16 packed-dot2 layers 2/3 ----
__global__ __launch_bounds__(256) void conv1_kernel(const float* __restrict__ p, const float* __restrict__ q,
        const int* __restrict__ idx,
        const float* __restrict__ sc1v, const float* __restrict__ sh1v,
        const float* __restrict__ w2, const float* __restrict__ b2,
        const float* __restrict__ sc2v, const float* __restrict__ sh2v,
        const float* __restrict__ w3, const float* __restrict__ b3,
        float* __restrict__ x1){
    __shared__ __align__(16) f16 hA[4][2][64];
    __shared__ __align__(16) f16 hB[4][2][64];
    int t = threadIdx.x, w = t >> 6, c = t & 63;
    f16x2 w2h[32], w3h[32];
#pragma unroll
    for (int f2 = 0; f2 < 32; f2++){
        w2h[f2] = f16x2{(f16)w2[(2*f2)*64 + c], (f16)w2[(2*f2+1)*64 + c]};
        w3h[f2] = f16x2{(f16)w3[(2*f2)*64 + c], (f16)w3[(2*f2+1)*64 + c]};
    }
    float sc1 = sc1v[c], sh1 = sh1v[c], sc2 = sc2v[c], sh2 = sh2v[c];
    float b2c = b2[c], b3c = b3[c];
    int node = blockIdx.x * 4 + w;
    int b = node >> 11;
    float pc = p[(size_t)node * 64 + c];
    const int* ip = idx + (size_t)node * Kn;
    float acc = -FLT_MAX;
    for (int k = 0; k < Kn; k += 2){
        bool two = (k + 1 < Kn);
        int j0 = ip[k];
        int j1 = ip[two ? k + 1 : k];
        float za = pc + q[((size_t)(b << 11) + j0) * 64 + c];
        float zb = pc + q[((size_t)(b << 11) + j1) * 64 + c];
        hA[w][0][c] = (f16)fmaxf(0.f, za * sc1 + sh1);
        hA[w][1][c] = (f16)fmaxf(0.f, zb * sc1 + sh1);
        const uint4* h40 = (const uint4*)hA[w][0];
        const uint4* h41 = (const uint4*)hA[w][1];
        float p00=0.f,p01=0.f,p02=0.f,p03=0.f, p10=0.f,p11=0.f,p12=0.f,p13=0.f;
#pragma unroll
        for (int i = 0; i < 8; i++){
            uint4 u0 = h40[i], u1 = h41[i];
            p00 = __builtin_amdgcn_fdot2(__builtin_bit_cast(f16x2, u0.x), w2h[4*i+0], p00, false);
            p10 = __builtin_amdgcn_fdot2(__builtin_bit_cast(f16x2, u1.x), w2h[4*i+0], p10, false);
            p01 = __builtin_amdgcn_fdot2(__builtin_bit_cast(f16x2, u0.y), w2h[4*i+1], p01, false);
            p11 = __builtin_amdgcn_fdot2(__builtin_bit_cast(f16x2, u1.y), w2h[4*i+1], p11, false);
            p02 = __builtin_amdgcn_fdot2(__builtin_bit_cast(f16x2, u0.z), w2h[4*i+2], p02, false);
            p12 = __builtin_amdgcn_fdot2(__builtin_bit_cast(f16x2, u1.z), w2h[4*i+2], p12, false);
            p03 = __builtin_amdgcn_fdot2(__builtin_bit_cast(f16x2, u0.w), w2h[4*i+3], p03, false);
            p13 = __builtin_amdgcn_fdot2(__builtin_bit_cast(f16x2, u1.w), w2h[4*i+3], p13, false);
        }
        float z20 = b2c + ((p00 + p01) + (p02 + p03));
        float z21 = b2c + ((p10 + p11) + (p12 + p13));
        hB[w][0][c] = (f16)fmaxf(0.f, z20 * sc2 + sh2);
        hB[w][1][c] = (f16)fmaxf(0.f, z21 * sc2 + sh2);
        const uint4* g40 = (const uint4*)hB[w][0];
        const uint4* g41 = (const uint4*)hB[w][1];
        float q00=0.f,q01=0.f,q02=0.f,q03=0.f, q10=0.f,q11=0.f,q12=0.f,q13=0.f;
#pragma unroll
        for (int i = 0; i < 8; i++){
            uint4 u0 = g40[i], u1 = g41[i];
            q00 = __builtin_amdgcn_fdot2(__builtin_bit_cast(f16x2, u0.x), w3h[4*i+0], q00, false);
            q10 = __builtin_amdgcn_fdot2(__builtin_bit_cast(f16x2, u1.x), w3h[4*i+0], q10, false);
            q01 = __builtin_amdgcn_fdot2(__builtin_bit_cast(f16x2, u0.y), w3h[4*i+1], q01, false);
            q11 = __builtin_amdgcn_fdot2(__builtin_bit_cast(f16x2, u1.y), w3h[4*i+1], q11, false);
            q02 = __builtin_amdgcn_fdot2(__builtin_bit_cast(f16x2, u0.z), w3h[4*i+2], q02, false);
            q12 = __builtin_amdgcn_fdot2(__builtin_bit_cast(f16x2, u1.z), w3h[4*i+2], q12, false);
            q03 = __builtin_amdgcn_fdot2(__builtin_bit_cast(f16x2, u0.w), w3h[4*i+3], q03, false);
            q13 = __builtin_amdgcn_fdot2(__builtin_bit_cast(f16x2, u1.w), w3h[4*i+3], q13, false);
        }
        float z30 = b3c + ((q00 + q01) + (q02 + q03));
        float z31 = b3c + ((q10 + q11) + (q12 + q13));
        acc = fmaxf(acc, z30);
        if (two) acc = fmaxf(acc, z31);
    }
    x1[(size_t)node * 64 + c] = acc;
}

// ---- pre2: u = x1@(W4a-W4b)+b4 (into x2 buffer), v = x1@W4b ----
__global__ __launch_bounds__(256) void pre2_kernel(const float* __restrict__ x1,
        const float* __restrict__ w4, const float* __restrict__ b4,
        float* __restrict__ u, float* __restrict__ v){
    __shared__ float x1s[16][64];
    int t = threadIdx.x;
    int c = t & 127, h = t >> 7;
    float wd[64], wb[64];
#pragma unroll
    for (int f = 0; f < 64; f++){
        float wbv = w4[(64 + f) * 128 + c];
        wb[f] = wbv;
        wd[f] = w4[f * 128 + c] - wbv;
    }
    float b4c = b4[c];
    int base = blockIdx.x * 16;
    for (int i = t; i < 16 * 64; i += 256)
        x1s[i >> 6][i & 63] = x1[(size_t)(base + (i >> 6)) * 64 + (i & 63)];
    __syncthreads();
    for (int n = 0; n < 8; n++){
        int node = base + h * 8 + n;
        const float4* xr = (const float4*)x1s[h * 8 + n];
        float u0 = 0.f, u1 = 0.f, v0 = 0.f, v1 = 0.f;
#pragma unroll
        for (int f4 = 0; f4 < 16; f4++){
            float4 xv = xr[f4];
            float pa = xv.x * wd[4*f4] + xv.y * wd[4*f4+1] + xv.z * wd[4*f4+2] + xv.w * wd[4*f4+3];
            float pb = xv.x * wb[4*f4] + xv.y * wb[4*f4+1] + xv.z * wb[4*f4+2] + xv.w * wb[4*f4+3];
            if (f4 & 1){ u1 += pa; v1 += pb; } else { u0 += pa; v0 += pb; }
        }
        u[(size_t)node * 128 + c] = b4c + u0 + u1;
        v[(size_t)node * 128 + c] = v0 + v1;
    }
}

// ---- gmax2: x2[i][c] = u[i][c] + max_k v[j_k][c]  (x2 holds u on entry) ----
__global__ __launch_bounds__(256) void gmax2_kernel(const float* __restrict__ v, const int* __restrict__ idx,
        float* __restrict__ x2){
    int t = threadIdx.x, g = t >> 7, c = t & 127;
    int node = blockIdx.x * 2 + g;
    int b = node >> 11;
    const int* ip = idx + (size_t)node * Kn;
    float vm = -FLT_MAX;
    for (int k = 0; k < Kn; k++){
        int j = ip[k];
        vm = fmaxf(vm, v[((size_t)(b << 11) + j) * 128 + c]);
    }
    x2[(size_t)node * 128 + c] += vm;
}

// ---- out = cat(x1,x2) @ w5 + b5, global max over nodes (encoded atomics) ----
__global__ __launch_bounds__(256) void outpool_kernel(const float* __restrict__ x1, const float* __restrict__ x2,
        const float* __restrict__ w5, const float* __restrict__ b5, unsigned* __restrict__ pooled){
    __shared__ float rows[8][192];
    int t = threadIdx.x;
    int node0 = blockIdx.x * 8;
    for (int i = t; i < 8 * 192; i += 256){
        int e = i / 192, f = i - e * 192;
        int nd = node0 + e;
        rows[e][f] = (f < 64) ? x1[(size_t)nd * 64 + f] : x2[(size_t)nd * 128 + f - 64];
    }
    __syncthreads();
    float z[8];
#pragma unroll
    for (int e = 0; e < 8; e++) z[e] = b5[t];
    for (int f = 0; f < 192; f++){
        float w = w5[f * 256 + t];
#pragma unroll
        for (int e = 0; e < 8; e++) z[e] += rows[e][f] * w;
    }
    float m = z[0];
#pragma unroll
    for (int e = 1; e < 8; e++) m = fmaxf(m, z[e]);
    int b = node0 >> 11;
    atomicMax(&pooled[b * 256 + t], enc_f(m));
}

// ---- head: decode pooled, MLP [256,128,64,4] with training-mode BN over 16 ----
__global__ __launch_bounds__(256) void head_kernel(const unsigned* __restrict__ pooledE,
        const float* __restrict__ w6, const float* __restrict__ b6, const float* __restrict__ g6, const float* __restrict__ bt6,
        const float* __restrict__ w7, const float* __restrict__ b7, const float* __restrict__ g7, const float* __restrict__ bt7,
        const float* __restrict__ w8, const float* __restrict__ b8, float* __restrict__ out){
    __shared__ float P[16][256];
    __shared__ float H6[16][128];
    __shared__ float H7[16][64];
    int t = threadIdx.x;
    for (int i = t; i < 16 * 256; i += 256) P[i >> 8][i & 255] = dec_f(pooledE[i]);
    __syncthreads();
    for (int i = t; i < 16 * 128; i += 256){
        int r = i >> 7, c = i & 127;
        float z = b6[c];
        for (int f = 0; f < 256; f++) z += P[r][f] * w6[f * 128 + c];
        H6[r][c] = z;
    }
    __syncthreads();
    if (t < 128){
        float s = 0.f, q = 0.f;
        for (int r = 0; r < 16; r++){ float v = H6[r][t]; s += v; q += v * v; }
        float mu = s * (1.f / 16.f);
        float var = q * (1.f / 16.f) - mu * mu;
        float sc = g6[t] / sqrtf(var + EPSV);
        float sh = bt6[t] - mu * sc;
        for (int r = 0; r < 16; r++) H6[r][t] = fmaxf(0.f, H6[r][t] * sc + sh);
    }
    __syncthreads();
    for (int i = t; i < 16 * 64; i += 256){
        int r = i >> 6, c = i & 63;
        float z = b7[c];
        for (int f = 0; f < 128; f++) z += H6[r][f] * w7[f * 64 + c];
        H7[r][c] = z;
    }
    __syncthreads();
    if (t < 64){
        float s = 0.f, q = 0.f;
        for (int r = 0; r < 16; r++){ float v = H7[r][t]; s += v; q += v * v; }
        float mu = s * (1.f / 16.f);
        float var = q * (1.f / 16.f) - mu * mu;
        float sc = g7[t] / sqrtf(var + EPSV);
        float sh = bt7[t] - mu * sc;
        for (int r = 0; r < 16; r++) H7[r][t] = fmaxf(0.f, H7[r][t] * sc + sh);
    }
    __syncthreads();
    if (t < 64){
        int r = t >> 2, c = t & 3;
        float z = b8[c];
        for (int f = 0; f < 64; f++) z += H7[r][f] * w8[f * 4 + c];
        out[t] = z;
    }
}

extern "C" void kernel_launch(void* const* d_in, const int* in_sizes, int n_in,
                              void* d_out, int out_size, void* d_ws, size_t ws_size,
                              hipStream_t stream){
    const float* x   = (const float*)d_in[0];
    const float* w1  = (const float*)d_in[1];
    const float* b1  = (const float*)d_in[2];
    const float* g1  = (const float*)d_in[3];
    const float* bt1 = (const float*)d_in[4];
    const float* w2  = (const float*)d_in[5];
    const float* b2  = (const float*)d_in[6];
    const float* g2  = (const float*)d_in[7];
    const float* bt2 = (const float*)d_in[8];
    const float* w3  = (const float*)d_in[9];
    const float* b3  = (const float*)d_in[10];
    const float* w4  = (const float*)d_in[11];
    const float* b4  = (const float*)d_in[12];
    const float* w5  = (const float*)d_in[13];
    const float* b5  = (const float*)d_in[14];
    const float* w6  = (const float*)d_in[15];
    const float* b6  = (const float*)d_in[16];
    const float* g6  = (const float*)d_in[17];
    const float* bt6 = (const float*)d_in[18];
    const float* w7  = (const float*)d_in[19];
    const float* b7  = (const float*)d_in[20];
    const float* g7  = (const float*)d_in[21];
    const float* bt7 = (const float*)d_in[22];
    const float* w8  = (const float*)d_in[23];
    const float* b8  = (const float*)d_in[24];
    float* out = (float*)d_out;

    char* ws = (char*)d_ws;
    size_t off = 0;
    auto alloc = [&](size_t bytes)->char*{
        char* p = ws + off;
        off += (bytes + 255) & ~(size_t)255;
        return p;
    };
    int*      idx1   = (int*)alloc((size_t)EDG * 4);
    int*      idx2   = (int*)alloc((size_t)EDG * 4);
    float*    sq1    = (float*)alloc((size_t)NODES * 4);
    float*    sq2    = (float*)alloc((size_t)NODES * 4);
    float*    x1     = (float*)alloc((size_t)NODES * 64 * 4);
    float*    x2     = (float*)alloc((size_t)NODES * 128 * 4);
    float*    sumP   = (float*)alloc((size_t)NSTATB * 64 * 4);
    float*    ssqP   = (float*)alloc((size_t)NSTATB * 64 * 4);
    float*    scale1 = (float*)alloc(64 * 4);
    float*    shift1 = (float*)alloc(64 * 4);
    float*    scale2 = (float*)alloc(64 * 4);
    float*    shift2 = (float*)alloc(64 * 4);
    unsigned* pooled = (unsigned*)alloc((size_t)Bn * 256 * 4);
    float*    p      = (float*)alloc((size_t)NODES * 64 * 4);
    float*    q      = (float*)alloc((size_t)NODES * 64 * 4);
    float*    v      = p;   // overlay: p,q are dead once conv1 finishes; v = 128 floats/node spans p+q

    hipMemsetAsync(pooled, 0, (size_t)Bn * 256 * 4, stream);

    sq_kernel<8><<<(NODES + 255) / 256, 256, 0, stream>>>(x, sq1);
    knn_kernel<8><<<NODES / 4, 256, 0, stream>>>(x, sq1, idx1);
    pre1_kernel<<<512, 256, 0, stream>>>(x, w1, b1, p, q);
    stats1_kernel<<<NSTATB, 256, 0, stream>>>(p, q, idx1, sumP, ssqP);
    finalize_kernel<<<1, 64, 0, stream>>>(sumP, ssqP, g1, bt1, scale1, shift1, 1.0f / (float)EDG);
    stats2_kernel<<<NSTATB, 256, 0, stream>>>(p, q, idx1, scale1, shift1, w2, b2, sumP, ssqP);
    finalize_kernel<<<1, 64, 0, stream>>>(sumP, ssqP, g2, bt2, scale2, shift2, 1.0f / (float)EDG);
    conv1_kernel<<<NODES / 4, 256, 0, stream>>>(p, q, idx1, scale1, shift1,
                                                w2, b2, scale2, shift2, w3, b3, x1);
    sq_kernel<64><<<(NODES + 255) / 256, 256, 0, stream>>>(x1, sq2);
    knn_kernel<64><<<NODES / 4, 256, 0, stream>>>(x1, sq2, idx2);
    pre2_kernel<<<NODES / 16, 256, 0, stream>>>(x1, w4, b4, x2, v);
    gmax2_kernel<<<NODES / 2, 256, 0, stream>>>(v, idx2, x2);
    outpool_kernel<<<NODES / 8, 256, 0, stream>>>(x1, x2, w5, b5, pooled);
    head_kernel<<<1, 256, 0, stream>>>(pooled, w6, b6, g6, bt6, w7, b7, g7, bt7, w8, b8, out);
}